// Round 5
// baseline (1657.745 us; speedup 1.0000x reference)
//
#include <hip/hip_runtime.h>
#include <hip/hip_bf16.h>
#include <stdint.h>

#define B_ 4
#define N_ 8192
#define D_ 128
#define E_ 262144

typedef __bf16 bf16x8 __attribute__((ext_vector_type(8)));
typedef unsigned short u16x8 __attribute__((ext_vector_type(8)));
typedef float f32x4 __attribute__((ext_vector_type(4)));

constexpr int BUCKET_CAP = 128;   // Poisson(32)/src; P(>=128) ~ 1e-40
constexpr int TILES = 8;          // 64-edge tiles per edge_mlp block
constexpr int GRID_MLP = E_ / (64 * TILES);   // 512 blocks = full residency

// ws layout (bytes):
constexpr size_t OFF_HB     = 0;          // bf16 h [B][N][D]         8,388,608
constexpr size_t OFF_W1T    = 8388608;    // bf16 W1^T [128][256]        65,536
constexpr size_t OFF_SCORES = 8454144;    // float4 scores [E]        4,194,304
constexpr size_t OFF_CNT    = 12648448;   // int cnt [N]                 32,768
constexpr size_t OFF_BASE   = 12681216;   // int base [N]                32,768
constexpr size_t OFF_BUCKET = 12713984;   // int bucket [N][128]      4,194,304
constexpr size_t OFF_ORDER  = 16908288;   // int order [E]            1,048,576

__device__ __forceinline__ unsigned short f2bf(float f) {
  union { float f; unsigned u; } v; v.f = f;
  unsigned r = v.u + 0x7fffu + ((v.u >> 16) & 1u);  // RNE
  return (unsigned short)(r >> 16);
}

__global__ void cast_h_k(const float* __restrict__ h, unsigned short* __restrict__ o) {
  int i = blockIdx.x * blockDim.x + threadIdx.x;   // 1,048,576 threads x 4 elems
  float4 v = reinterpret_cast<const float4*>(h)[i];
  ushort4 r;
  r.x = f2bf(v.x); r.y = f2bf(v.y); r.z = f2bf(v.z); r.w = f2bf(v.w);
  reinterpret_cast<ushort4*>(o)[i] = r;
}

__global__ void tw1_k(const float* __restrict__ W1, unsigned short* __restrict__ o) {
  int i = blockIdx.x * blockDim.x + threadIdx.x;   // 32768: i = d*256 + k
  int d = i >> 8, k = i & 255;
  o[i] = f2bf(W1[k * 128 + d]);
}

// append every edge to its src bucket (order within bucket irrelevant)
__global__ void place_k(const int* __restrict__ ei,
                        int* __restrict__ cnt, int* __restrict__ bucket) {
  int e = blockIdx.x * blockDim.x + threadIdx.x;
  int s = ei[e];
  int pos = atomicAdd(&cnt[s], 1);
  if (pos < BUCKET_CAP) bucket[s * BUCKET_CAP + pos] = e;
}

// exclusive prefix sum of clamped counts -> base[]
__global__ void prefix_k(const int* __restrict__ cnt, int* __restrict__ base) {
  __shared__ int sc[256];
  const int t = threadIdx.x;
  int c[32];
  int local = 0;
  #pragma unroll
  for (int j = 0; j < 32; ++j) {
    int v = cnt[t * 32 + j];
    v = v < BUCKET_CAP ? v : BUCKET_CAP;
    c[j] = v; local += v;
  }
  sc[t] = local;
  __syncthreads();
  #pragma unroll
  for (int off = 1; off < 256; off <<= 1) {
    int v = (t >= off) ? sc[t - off] : 0;
    __syncthreads();
    sc[t] += v;
    __syncthreads();
  }
  int run = sc[t] - local;                  // exclusive
  #pragma unroll
  for (int j = 0; j < 32; ++j) { base[t * 32 + j] = run; run += c[j]; }
}

// flatten buckets -> src-grouped order[]
__global__ void order_build_k(const int* __restrict__ cnt, const int* __restrict__ base,
                              const int* __restrict__ bucket, int* __restrict__ order) {
  int s = blockIdx.x * blockDim.x + threadIdx.x;   // 8192 threads
  int n = cnt[s]; n = n < BUCKET_CAP ? n : BUCKET_CAP;
  int b0 = base[s];
  for (int j = 0; j < n; ++j) order[b0 + j] = bucket[s * BUCKET_CAP + j];
}

// 512 threads, 8 waves; TILES tiles of 64 edges; M=256 rows (row=e_local*4+b),
// K=256, N=128. Wave w owns rows [w*32, w*32+32). W1^T staged once per block.
__global__ __launch_bounds__(512, 4) void edge_mlp_k(
    const int* __restrict__ ei,
    const int* __restrict__ order,
    const unsigned short* __restrict__ hb,    // bf16 bits [B][N][D]
    const unsigned short* __restrict__ w1t,   // bf16 bits [128][256]
    const float* __restrict__ b1,
    const float* __restrict__ w2,
    const float* __restrict__ b2,
    f32x4* __restrict__ scores) {             // [E] = {b0,b1,b2,b3}
  __shared__ char lds[65536];                 // W1^T, XOR-swizzled rows of 512 B
  const int tid  = threadIdx.x;
  const int lane = tid & 63;
  const int wid  = tid >> 6;                  // 0..7
  const int l15  = lane & 15;
  const int lg   = lane >> 4;

  {
    const uint4* g = reinterpret_cast<const uint4*>(w1t);
    #pragma unroll
    for (int it = 0; it < 8; ++it) {
      int i = it * 512 + tid;                 // uint4 index, 4096 total
      uint4 v = g[i];
      int byte = i * 16;
      int dd = byte >> 9;
      int within = byte & 511;
      *reinterpret_cast<uint4*>(&lds[dd * 512 + (within ^ ((dd & 7) << 4))]) = v;
    }
  }
  __syncthreads();

  // preload epilogue constants once
  float b1v[8], w2v[8];
  #pragma unroll
  for (int n = 0; n < 8; ++n) {
    int col = n * 16 + l15;
    b1v[n] = b1[col];
    w2v[n] = w2[col];
  }
  const float b2v = b2[0];
  const int kg = 8 * lg;

  #pragma unroll 1
  for (int tile = 0; tile < TILES; ++tile) {
    const int t0 = (blockIdx.x * TILES + tile) * 64;

    unsigned offS[2], offD[2];
    #pragma unroll
    for (int m = 0; m < 2; ++m) {
      int row = wid * 32 + m * 16 + l15;
      int e = order[t0 + (row >> 2)];
      int b = row & 3;
      offS[m] = ((unsigned)b * N_ + (unsigned)ei[e]) * D_;
      offD[m] = ((unsigned)b * N_ + (unsigned)ei[E_ + e]) * D_;
    }

    f32x4 acc[2][8];
    #pragma unroll
    for (int m = 0; m < 2; ++m)
      #pragma unroll
      for (int n = 0; n < 8; ++n)
        acc[m][n] = (f32x4){0.f, 0.f, 0.f, 0.f};

    #pragma unroll
    for (int ks = 0; ks < 8; ++ks) {
      bf16x8 a[2];
      const int kin = (ks & 3) * 32 + kg;
      #pragma unroll
      for (int m = 0; m < 2; ++m) {
        unsigned off = (ks < 4 ? offS[m] : offD[m]) + (unsigned)kin;
        u16x8 u = *reinterpret_cast<const u16x8*>(hb + off);
        a[m] = __builtin_bit_cast(bf16x8, u);
      }
      const int kb = ks * 64 + 16 * lg;
      #pragma unroll
      for (int n = 0; n < 8; ++n) {
        int dd = n * 16 + l15;
        uint4 v = *reinterpret_cast<const uint4*>(&lds[dd * 512 + (kb ^ ((dd & 7) << 4))]);
        bf16x8 bfr = __builtin_bit_cast(bf16x8, v);
        acc[0][n] = __builtin_amdgcn_mfma_f32_16x16x32_bf16(a[0], bfr, acc[0][n], 0, 0, 0);
        acc[1][n] = __builtin_amdgcn_mfma_f32_16x16x32_bf16(a[1], bfr, acc[1][n], 0, 0, 0);
      }
    }

    float sc[2][4];
    #pragma unroll
    for (int m = 0; m < 2; ++m)
      #pragma unroll
      for (int i = 0; i < 4; ++i) sc[m][i] = 0.f;
    #pragma unroll
    for (int n = 0; n < 8; ++n)
      #pragma unroll
      for (int m = 0; m < 2; ++m)
        #pragma unroll
        for (int i = 0; i < 4; ++i) {
          float v = acc[m][n][i] + b1v[n];
          float sv = v / (1.f + __expf(-v));    // SiLU
          sc[m][i] += sv * w2v[n];
        }
    #pragma unroll
    for (int m = 0; m < 2; ++m)
      #pragma unroll
      for (int i = 0; i < 4; ++i) {
        float v = sc[m][i];
        v += __shfl_xor(v, 1, 64);
        v += __shfl_xor(v, 2, 64);
        v += __shfl_xor(v, 4, 64);
        v += __shfl_xor(v, 8, 64);
        sc[m][i] = v;
      }
    if (l15 == 0) {
      // lane's 4 acc regs = rows base..base+3 = the 4 batches of one edge
      #pragma unroll
      for (int m = 0; m < 2; ++m) {
        int base_row = wid * 32 + m * 16 + 4 * lg;
        int e_w = order[t0 + (base_row >> 2)];
        scores[e_w] = (f32x4){sc[m][0] + b2v, sc[m][1] + b2v, sc[m][2] + b2v, sc[m][3] + b2v};
      }
    }
  }
}

// One block per src row. Dedupe (max-e wins) in LDS, mark idx8[dst]=t+1,
// then stream all 4 batches' rows with each float4 written EXACTLY ONCE (NT).
__global__ __launch_bounds__(256, 8) void out_writer_k(
    const int* __restrict__ ei,
    const int* __restrict__ cnt,
    const int* __restrict__ bucket,
    const f32x4* __restrict__ scores,
    float* __restrict__ out) {
  __shared__ int dst_l[BUCKET_CAP];
  __shared__ int e_l[BUCKET_CAP];
  __shared__ float sc4[BUCKET_CAP][4];
  __shared__ unsigned int idx32[2048];        // u8 mark per dst elem (8192)
  const int t = threadIdx.x;
  const int src = blockIdx.x;
  int n = cnt[src];
  n = n < BUCKET_CAP ? n : BUCKET_CAP;
  if (t < n) {
    int e = bucket[src * BUCKET_CAP + t];
    e_l[t] = e;
    dst_l[t] = ei[E_ + e];
    f32x4 s = scores[e];
    sc4[t][0] = s[0]; sc4[t][1] = s[1]; sc4[t][2] = s[2]; sc4[t][3] = s[3];
  }
  #pragma unroll
  for (int k = 0; k < 8; ++k) idx32[t + 256 * k] = 0u;
  __syncthreads();
  if (t < n) {
    int dst = dst_l[t], e = e_l[t];
    bool win = true;
    for (int j = 0; j < n; ++j)
      win = win && !(dst_l[j] == dst && e_l[j] > e);
    if (win) reinterpret_cast<unsigned char*>(idx32)[dst] = (unsigned char)(t + 1);
  }
  __syncthreads();

  const size_t rowbase = (size_t)src * N_;
  #pragma unroll
  for (int b = 0; b < 4; ++b) {
    f32x4* po = reinterpret_cast<f32x4*>(out + (size_t)b * ((size_t)N_ * N_) + rowbase);
    #pragma unroll
    for (int k = 0; k < 8; ++k) {
      int c = t + 256 * k;                    // float4 chunk: dsts [4c, 4c+4)
      unsigned m4 = idx32[c];
      f32x4 v = (f32x4){0.f, 0.f, 0.f, 0.f};
      if (m4) {
        #pragma unroll
        for (int i = 0; i < 4; ++i) {
          unsigned mj = (m4 >> (8 * i)) & 255u;
          if (mj) v[i] = sc4[mj - 1][b];
        }
      }
      __builtin_nontemporal_store(v, po + c);
    }
  }
}

extern "C" void kernel_launch(void* const* d_in, const int* in_sizes, int n_in,
                              void* d_out, int out_size, void* d_ws, size_t ws_size,
                              hipStream_t stream) {
  const float* h  = (const float*)d_in[0];
  const int*   ei = (const int*)d_in[1];     // harness stores integer inputs as int32
  const float* W1 = (const float*)d_in[2];
  const float* b1 = (const float*)d_in[3];
  const float* W2 = (const float*)d_in[4];
  const float* b2 = (const float*)d_in[5];
  float* out = (float*)d_out;
  char*  ws  = (char*)d_ws;

  unsigned short* hb     = (unsigned short*)(ws + OFF_HB);
  unsigned short* w1t    = (unsigned short*)(ws + OFF_W1T);
  f32x4*          scores = (f32x4*)(ws + OFF_SCORES);
  int*            cnt    = (int*)(ws + OFF_CNT);
  int*            base   = (int*)(ws + OFF_BASE);
  int*            bucket = (int*)(ws + OFF_BUCKET);
  int*            order  = (int*)(ws + OFF_ORDER);

  (void)hipMemsetAsync(cnt, 0, (size_t)N_ * 4, stream);
  (void)hipMemsetAsync(order, 0, (size_t)E_ * 4, stream);  // safe pad if overflow

  cast_h_k<<<4096, 256, 0, stream>>>(h, hb);
  tw1_k<<<128, 256, 0, stream>>>(W1, w1t);
  place_k<<<E_ / 256, 256, 0, stream>>>(ei, cnt, bucket);
  prefix_k<<<1, 256, 0, stream>>>(cnt, base);
  order_build_k<<<32, 256, 0, stream>>>(cnt, base, bucket, order);
  edge_mlp_k<<<GRID_MLP, 512, 0, stream>>>(ei, order, hb, w1t, b1, W2, b2, scores);
  out_writer_k<<<N_, 256, 0, stream>>>(ei, cnt, bucket, scores, out);
}